// Round 1
// baseline (3823.066 us; speedup 1.0000x reference)
//
#include <hip/hip_runtime.h>

// ---------------------------------------------------------------------------
// res_rand_GAE: 2-layer GCN (two self loops per node) + residual + MLP head.
// All fp32 exact-path. Outputs: x [N,128] then A [N,1] concatenated in d_out.
// ---------------------------------------------------------------------------

static inline int cdiv_ll(long long a, long long b) { return (int)((a + b - 1) / b); }

// ---- degree / norm ---------------------------------------------------------

__global__ __launch_bounds__(256) void deg_init_kernel(float* __restrict__ deg, int N) {
    int i = blockIdx.x * blockDim.x + threadIdx.x;
    if (i < N) deg[i] = 2.0f;   // two self loops per node
}

__global__ __launch_bounds__(256) void deg_count_kernel(const int* __restrict__ dst,
                                                        float* __restrict__ deg, int E) {
    int e = blockIdx.x * blockDim.x + threadIdx.x;
    if (e < E) atomicAdd(&deg[dst[e]], 1.0f);
}

__global__ __launch_bounds__(256) void dinv_kernel(float* __restrict__ deg, int N) {
    int i = blockIdx.x * blockDim.x + threadIdx.x;
    if (i < N) {
        float d = deg[i];
        deg[i] = (d > 0.0f) ? rsqrtf(d) : 0.0f;   // in-place deg -> dinv
    }
}

// ---- fp32 tiled GEMM: C[M,Nn] = A[M,K] @ B[K,Nn], row-major ---------------
// 64x64 tile, BK=16, 256 threads, 4x4 per thread. Nn, K multiples of 64/16.

__global__ __launch_bounds__(256) void sgemm64(const float* __restrict__ A,
                                               const float* __restrict__ B,
                                               float* __restrict__ C,
                                               int M, int Nn, int K) {
    __shared__ float As[16][68];
    __shared__ float Bs[16][68];
    const int t = threadIdx.x;
    const int bm = blockIdx.y * 64;
    const int bn = blockIdx.x * 64;
    const int tm = (t >> 4) << 2;       // 0..60
    const int tn = (t & 15) << 2;       // 0..60

    const int arow = t >> 2;            // 0..63
    const int akq  = (t & 3) << 2;      // 0,4,8,12
    const int bkr  = t >> 4;            // 0..15
    const int bnq  = (t & 15) << 2;     // 0..60

    float acc[4][4] = {};

    for (int kk = 0; kk < K; kk += 16) {
        float4 av;
        if (bm + arow < M)
            av = *(const float4*)(A + (size_t)(bm + arow) * K + kk + akq);
        else
            av = make_float4(0.f, 0.f, 0.f, 0.f);
        As[akq + 0][arow] = av.x;
        As[akq + 1][arow] = av.y;
        As[akq + 2][arow] = av.z;
        As[akq + 3][arow] = av.w;

        float4 bv = *(const float4*)(B + (size_t)(kk + bkr) * Nn + bn + bnq);
        *(float4*)&Bs[bkr][bnq] = bv;

        __syncthreads();

#pragma unroll
        for (int k = 0; k < 16; ++k) {
            float a0 = As[k][tm + 0], a1 = As[k][tm + 1];
            float a2 = As[k][tm + 2], a3 = As[k][tm + 3];
            float b0 = Bs[k][tn + 0], b1 = Bs[k][tn + 1];
            float b2 = Bs[k][tn + 2], b3 = Bs[k][tn + 3];
            acc[0][0] = fmaf(a0, b0, acc[0][0]);
            acc[0][1] = fmaf(a0, b1, acc[0][1]);
            acc[0][2] = fmaf(a0, b2, acc[0][2]);
            acc[0][3] = fmaf(a0, b3, acc[0][3]);
            acc[1][0] = fmaf(a1, b0, acc[1][0]);
            acc[1][1] = fmaf(a1, b1, acc[1][1]);
            acc[1][2] = fmaf(a1, b2, acc[1][2]);
            acc[1][3] = fmaf(a1, b3, acc[1][3]);
            acc[2][0] = fmaf(a2, b0, acc[2][0]);
            acc[2][1] = fmaf(a2, b1, acc[2][1]);
            acc[2][2] = fmaf(a2, b2, acc[2][2]);
            acc[2][3] = fmaf(a2, b3, acc[2][3]);
            acc[3][0] = fmaf(a3, b0, acc[3][0]);
            acc[3][1] = fmaf(a3, b1, acc[3][1]);
            acc[3][2] = fmaf(a3, b2, acc[3][2]);
            acc[3][3] = fmaf(a3, b3, acc[3][3]);
        }
        __syncthreads();
    }

#pragma unroll
    for (int i = 0; i < 4; ++i) {
        int r = bm + tm + i;
        if (r < M) {
            *(float4*)(C + (size_t)r * Nn + bn + tn) =
                make_float4(acc[i][0], acc[i][1], acc[i][2], acc[i][3]);
        }
    }
}

// ---- self-loop init: agg[i][:] = h[i][:] * (2 * dinv[i]^2) -----------------

template <int F4>   // float4s per row
__global__ __launch_bounds__(256) void self_init_kernel(const float* __restrict__ h,
                                                        const float* __restrict__ dinv,
                                                        float* __restrict__ agg, int N) {
    long long tid = (long long)blockIdx.x * blockDim.x + threadIdx.x;
    long long total = (long long)N * F4;
    if (tid >= total) return;
    int i  = (int)(tid / F4);
    int f4 = (int)(tid % F4);
    float dv = dinv[i];
    float c = 2.0f * dv * dv;
    float4 v = *(const float4*)(h + (size_t)i * (F4 * 4) + f4 * 4);
    v.x *= c; v.y *= c; v.z *= c; v.w *= c;
    *(float4*)(agg + (size_t)i * (F4 * 4) + f4 * 4) = v;
}

// ---- edge scatter: agg[dst] += h[src] * dinv[src]*dinv[dst] ----------------

template <int F4>
__global__ __launch_bounds__(256) void edge_scatter_kernel(const float* __restrict__ h,
                                                           const int* __restrict__ src,
                                                           const int* __restrict__ dst,
                                                           const float* __restrict__ dinv,
                                                           float* __restrict__ agg, int E) {
    long long tid = (long long)blockIdx.x * blockDim.x + threadIdx.x;
    long long total = (long long)E * F4;
    if (tid >= total) return;
    int e  = (int)(tid / F4);
    int f4 = (int)(tid % F4);
    int s = src[e];
    int d = dst[e];
    float c = dinv[s] * dinv[d];
    float4 v = *(const float4*)(h + (size_t)s * (F4 * 4) + f4 * 4);
    float* ap = agg + (size_t)d * (F4 * 4) + f4 * 4;
    atomicAdd(ap + 0, v.x * c);
    atomicAdd(ap + 1, v.y * c);
    atomicAdd(ap + 2, v.z * c);
    atomicAdd(ap + 3, v.w * c);
}

// ---- x = relu(x + b[f]) in-place -------------------------------------------

template <int F4>
__global__ __launch_bounds__(256) void bias_relu_kernel(float* __restrict__ x,
                                                        const float* __restrict__ b, int N) {
    long long tid = (long long)blockIdx.x * blockDim.x + threadIdx.x;
    long long total = (long long)N * F4;
    if (tid >= total) return;
    int f4 = (int)(tid % F4);
    float4 v = *((float4*)x + tid);
    float4 bb = *((const float4*)b + f4);
    v.x = fmaxf(v.x + bb.x, 0.f);
    v.y = fmaxf(v.y + bb.y, 0.f);
    v.z = fmaxf(v.z + bb.z, 0.f);
    v.w = fmaxf(v.w + bb.w, 0.f);
    *((float4*)x + tid) = v;
}

// ---- x = relu(agg2 + b2) + hres + bres  (hres already in out, in-place) ----

template <int F4>
__global__ __launch_bounds__(256) void final_x_kernel(const float* __restrict__ agg2,
                                                      const float* __restrict__ b2,
                                                      const float* __restrict__ bres,
                                                      float* __restrict__ out, int N) {
    long long tid = (long long)blockIdx.x * blockDim.x + threadIdx.x;
    long long total = (long long)N * F4;
    if (tid >= total) return;
    int f4 = (int)(tid % F4);
    float4 a = *((const float4*)agg2 + tid);
    float4 h = *((float4*)out + tid);
    float4 b = *((const float4*)b2 + f4);
    float4 r = *((const float4*)bres + f4);
    float4 o;
    o.x = fmaxf(a.x + b.x, 0.f) + h.x + r.x;
    o.y = fmaxf(a.y + b.y, 0.f) + h.y + r.y;
    o.z = fmaxf(a.z + b.z, 0.f) + h.z + r.z;
    o.w = fmaxf(a.w + b.w, 0.f) + h.w + r.w;
    *((float4*)out + tid) = o;
}

// ---- MLP head: A[i] = relu(x[i]@Wfc1 + bfc1) @ Wfc2 + bfc2 -----------------
// 8 nodes per block; thread j owns hidden unit j (256 hidden).

__global__ __launch_bounds__(256) void head_kernel(const float* __restrict__ x,
                                                   const float* __restrict__ Wfc1,
                                                   const float* __restrict__ bfc1,
                                                   const float* __restrict__ Wfc2,
                                                   const float* __restrict__ bfc2,
                                                   float* __restrict__ A, int N) {
    const int NB = 8;
    __shared__ float xs[NB][128];
    __shared__ float red[256];
    const int t = threadIdx.x;
    const int base = blockIdx.x * NB;

    {   // load NB rows (NB*128 = 1024 floats = 256 float4)
        int node = t >> 5;
        int f4   = t & 31;
        float4 v = make_float4(0.f, 0.f, 0.f, 0.f);
        if (base + node < N)
            v = *((const float4*)(x + (size_t)(base + node) * 128) + f4);
        *((float4*)&xs[node][0] + f4) = v;
    }
    __syncthreads();

    float acc[NB] = {};
#pragma unroll 8
    for (int k = 0; k < 128; ++k) {
        float wv = Wfc1[k * 256 + t];
#pragma unroll
        for (int n = 0; n < NB; ++n) acc[n] = fmaf(xs[n][k], wv, acc[n]);
    }
    float bf = bfc1[t];
    float w2 = Wfc2[t];

    for (int n = 0; n < NB; ++n) {
        float p = fmaxf(acc[n] + bf, 0.f) * w2;
        red[t] = p;
        __syncthreads();
        if (t < 128) red[t] += red[t + 128];
        __syncthreads();
        if (t < 64) {
            float v = red[t] + red[t + 64];
            for (int o = 32; o; o >>= 1) v += __shfl_down(v, o);
            if (t == 0 && base + n < N) A[base + n] = v + bfc2[0];
        }
        __syncthreads();
    }
}

// ---------------------------------------------------------------------------

extern "C" void kernel_launch(void* const* d_in, const int* in_sizes, int n_in,
                              void* d_out, int out_size, void* d_ws, size_t ws_size,
                              hipStream_t stream) {
    const float* emb  = (const float*)d_in[0];
    const int*   eidx = (const int*)d_in[1];
    const float* W1   = (const float*)d_in[2];
    const float* b1   = (const float*)d_in[3];
    const float* W2   = (const float*)d_in[4];
    const float* b2   = (const float*)d_in[5];
    const float* Wres = (const float*)d_in[6];
    const float* bres = (const float*)d_in[7];
    const float* Wfc1 = (const float*)d_in[8];
    const float* bfc1 = (const float*)d_in[9];
    const float* Wfc2 = (const float*)d_in[10];
    const float* bfc2 = (const float*)d_in[11];

    const int N = in_sizes[0] / 128;
    const int E = in_sizes[1] / 2;
    const int* srcv = eidx;        // edge_index[0]
    const int* dstv = eidx + E;    // edge_index[1]

    float* out  = (float*)d_out;
    float* xout = out;                       // [N,128]
    float* Aout = out + (size_t)N * 128;     // [N]

    // workspace layout (floats): dinv[N] | h1[N*512] | agg1[N*512]
    // h1's region is reused for h2[N*128] + agg2[N*128] after x1 is computed.
    float* ws   = (float*)d_ws;
    float* dinv = ws;
    float* h1   = dinv + N;
    float* agg1 = h1 + (size_t)N * 512;      // becomes x1 in-place
    float* h2   = h1;                         // reuse
    float* agg2 = h1 + (size_t)N * 128;       // reuse

    const int T = 256;

    // 1) degrees -> dinv
    deg_init_kernel<<<cdiv_ll(N, T), T, 0, stream>>>(dinv, N);
    deg_count_kernel<<<cdiv_ll(E, T), T, 0, stream>>>(dstv, dinv, E);
    dinv_kernel<<<cdiv_ll(N, T), T, 0, stream>>>(dinv, N);

    // 2) h1 = emb @ W1   [N,512]
    sgemm64<<<dim3(512 / 64, cdiv_ll(N, 64)), T, 0, stream>>>(emb, W1, h1, N, 512, 128);

    // 3) agg1 = selfloops + edge scatter; x1 = relu(agg1 + b1) in-place
    self_init_kernel<128><<<cdiv_ll((long long)N * 128, T), T, 0, stream>>>(h1, dinv, agg1, N);
    edge_scatter_kernel<128><<<cdiv_ll((long long)E * 128, T), T, 0, stream>>>(h1, srcv, dstv, dinv, agg1, E);
    bias_relu_kernel<128><<<cdiv_ll((long long)N * 128, T), T, 0, stream>>>(agg1, b1, N);

    // 4) h2 = x1 @ W2 [N,128]; hres = x1 @ Wres -> d_out
    sgemm64<<<dim3(128 / 64, cdiv_ll(N, 64)), T, 0, stream>>>(agg1, W2, h2, N, 128, 512);
    sgemm64<<<dim3(128 / 64, cdiv_ll(N, 64)), T, 0, stream>>>(agg1, Wres, xout, N, 128, 512);

    // 5) agg2 = selfloops + edge scatter on h2
    self_init_kernel<32><<<cdiv_ll((long long)N * 32, T), T, 0, stream>>>(h2, dinv, agg2, N);
    edge_scatter_kernel<32><<<cdiv_ll((long long)E * 32, T), T, 0, stream>>>(h2, srcv, dstv, dinv, agg2, E);

    // 6) x = relu(agg2 + b2) + hres + bres   (in-place over hres in d_out)
    final_x_kernel<32><<<cdiv_ll((long long)N * 32, T), T, 0, stream>>>(agg2, b2, bres, xout, N);

    // 7) head: A = relu(x@Wfc1 + bfc1) @ Wfc2 + bfc2
    head_kernel<<<cdiv_ll(N, 8), T, 0, stream>>>(xout, Wfc1, bfc1, Wfc2, bfc2, Aout, N);
}

// Round 2
// 534.242 us; speedup vs baseline: 7.1561x; 7.1561x over previous
//
#include <hip/hip_runtime.h>

// ---------------------------------------------------------------------------
// res_rand_GAE: 2-layer GCN (two self loops per node) + residual + MLP head.
// Round 2: CSR-based atomic-free aggregation + layer-1 reorder S@(X@W)=(S@X)@W.
// Outputs: x [N,128] then A [N,1] concatenated in d_out. All fp32 exact-path.
// ---------------------------------------------------------------------------

static inline int cdiv_ll(long long a, long long b) { return (int)((a + b - 1) / b); }

// ---- CSR build -------------------------------------------------------------

__global__ __launch_bounds__(256) void zero_i32_kernel(int* __restrict__ p, int n) {
    int i = blockIdx.x * 256 + threadIdx.x;
    if (i < n) p[i] = 0;
}

__global__ __launch_bounds__(256) void hist_kernel(const int* __restrict__ dst,
                                                   int* __restrict__ cnt, int E) {
    int e = blockIdx.x * 256 + threadIdx.x;
    if (e < E) atomicAdd(&cnt[dst[e]], 1);
}

// per-block exclusive scan of cnt -> excl, block totals -> bsum
__global__ __launch_bounds__(256) void scanA_kernel(const int* __restrict__ cnt,
                                                    int* __restrict__ excl,
                                                    int* __restrict__ bsum, int N) {
    __shared__ int tmp[256];
    int i = blockIdx.x * 256 + threadIdx.x;
    int v = (i < N) ? cnt[i] : 0;
    tmp[threadIdx.x] = v;
    __syncthreads();
    for (int o = 1; o < 256; o <<= 1) {
        int t = (threadIdx.x >= (unsigned)o) ? tmp[threadIdx.x - o] : 0;
        __syncthreads();
        tmp[threadIdx.x] += t;
        __syncthreads();
    }
    if (i < N) excl[i] = tmp[threadIdx.x] - v;
    if (threadIdx.x == 255) bsum[blockIdx.x] = tmp[255];
}

// single-block exclusive scan of bsum (nb <= 256)
__global__ __launch_bounds__(256) void scanB_kernel(int* __restrict__ bsum, int nb) {
    __shared__ int tmp[256];
    int v = (threadIdx.x < (unsigned)nb) ? bsum[threadIdx.x] : 0;
    tmp[threadIdx.x] = v;
    __syncthreads();
    for (int o = 1; o < 256; o <<= 1) {
        int t = (threadIdx.x >= (unsigned)o) ? tmp[threadIdx.x - o] : 0;
        __syncthreads();
        tmp[threadIdx.x] += t;
        __syncthreads();
    }
    if (threadIdx.x < (unsigned)nb) bsum[threadIdx.x] = tmp[threadIdx.x] - v;
}

// rowptr = excl + bsum[blk]; cursor = rowptr; dinv = rsqrt(cnt+2); rowptr[N]=E
__global__ __launch_bounds__(256) void scanC_kernel(const int* __restrict__ excl,
                                                    const int* __restrict__ bsum,
                                                    const int* __restrict__ cnt,
                                                    int* __restrict__ rowptr,
                                                    int* __restrict__ cursor,
                                                    float* __restrict__ dinv,
                                                    int N, int E) {
    int i = blockIdx.x * 256 + threadIdx.x;
    if (i < N) {
        int r = excl[i] + bsum[blockIdx.x];
        rowptr[i] = r;
        cursor[i] = r;
        dinv[i] = rsqrtf((float)cnt[i] + 2.0f);   // + two self loops
    }
    if (i == 0) rowptr[N] = E;
}

__global__ __launch_bounds__(256) void fill_kernel(const int* __restrict__ src,
                                                   const int* __restrict__ dst,
                                                   const float* __restrict__ dinv,
                                                   int* __restrict__ cursor,
                                                   int* __restrict__ csr_src,
                                                   float* __restrict__ csr_w, int E) {
    int e = blockIdx.x * 256 + threadIdx.x;
    if (e >= E) return;
    int s = src[e], d = dst[e];
    int idx = atomicAdd(&cursor[d], 1);
    csr_src[idx] = s;
    csr_w[idx] = dinv[s] * dinv[d];
}

// ---- wave-per-node aggregation, F=128 --------------------------------------
// out[i][:] = 2*dinv[i]^2 * h[i][:] + sum_{e in CSR row i} w_e * h[src_e][:]

__global__ __launch_bounds__(256) void agg128_kernel(const float* __restrict__ h,
                                                     const int* __restrict__ rowptr,
                                                     const int* __restrict__ csr_src,
                                                     const float* __restrict__ csr_w,
                                                     const float* __restrict__ dinv,
                                                     float* __restrict__ out, int N) {
    int wid  = (blockIdx.x * blockDim.x + threadIdx.x) >> 6;
    int lane = threadIdx.x & 63;
    if (wid >= N) return;
    const float2* hp = (const float2*)h;
    float dv = dinv[wid];
    float2 hv = hp[(size_t)wid * 64 + lane];
    float c0 = 2.0f * dv * dv;
    float ax = hv.x * c0, ay = hv.y * c0;
    int e = rowptr[wid], e1 = rowptr[wid + 1];
    for (; e + 1 < e1; e += 2) {
        int   s0 = csr_src[e],  s1 = csr_src[e + 1];
        float w0 = csr_w[e],    w1 = csr_w[e + 1];
        float2 v0 = hp[(size_t)s0 * 64 + lane];
        float2 v1 = hp[(size_t)s1 * 64 + lane];
        ax = fmaf(v0.x, w0, ax); ay = fmaf(v0.y, w0, ay);
        ax = fmaf(v1.x, w1, ax); ay = fmaf(v1.y, w1, ay);
    }
    if (e < e1) {
        int s0 = csr_src[e]; float w0 = csr_w[e];
        float2 v0 = hp[(size_t)s0 * 64 + lane];
        ax = fmaf(v0.x, w0, ax); ay = fmaf(v0.y, w0, ay);
    }
    ((float2*)out)[(size_t)wid * 64 + lane] = make_float2(ax, ay);
}

// ---- fp32 tiled GEMM with optional bias+relu epilogue ----------------------
// C[M,Nn] = op(A[M,K] @ B[K,Nn] (+ bias)), 64x64 tile, BK=16, 256 thr, 4x4/thr

__global__ __launch_bounds__(256) void sgemm64(const float* __restrict__ A,
                                               const float* __restrict__ B,
                                               float* __restrict__ C,
                                               int M, int Nn, int K,
                                               const float* __restrict__ bias,
                                               int relu) {
    __shared__ float As[16][68];
    __shared__ float Bs[16][68];
    const int t = threadIdx.x;
    const int bm = blockIdx.y * 64;
    const int bn = blockIdx.x * 64;
    const int tm = (t >> 4) << 2;
    const int tn = (t & 15) << 2;

    const int arow = t >> 2;
    const int akq  = (t & 3) << 2;
    const int bkr  = t >> 4;
    const int bnq  = (t & 15) << 2;

    float acc[4][4] = {};

    for (int kk = 0; kk < K; kk += 16) {
        float4 av;
        if (bm + arow < M)
            av = *(const float4*)(A + (size_t)(bm + arow) * K + kk + akq);
        else
            av = make_float4(0.f, 0.f, 0.f, 0.f);
        As[akq + 0][arow] = av.x;
        As[akq + 1][arow] = av.y;
        As[akq + 2][arow] = av.z;
        As[akq + 3][arow] = av.w;

        float4 bv = *(const float4*)(B + (size_t)(kk + bkr) * Nn + bn + bnq);
        *(float4*)&Bs[bkr][bnq] = bv;

        __syncthreads();

#pragma unroll
        for (int k = 0; k < 16; ++k) {
            float a0 = As[k][tm + 0], a1 = As[k][tm + 1];
            float a2 = As[k][tm + 2], a3 = As[k][tm + 3];
            float b0 = Bs[k][tn + 0], b1 = Bs[k][tn + 1];
            float b2 = Bs[k][tn + 2], b3 = Bs[k][tn + 3];
            acc[0][0] = fmaf(a0, b0, acc[0][0]);
            acc[0][1] = fmaf(a0, b1, acc[0][1]);
            acc[0][2] = fmaf(a0, b2, acc[0][2]);
            acc[0][3] = fmaf(a0, b3, acc[0][3]);
            acc[1][0] = fmaf(a1, b0, acc[1][0]);
            acc[1][1] = fmaf(a1, b1, acc[1][1]);
            acc[1][2] = fmaf(a1, b2, acc[1][2]);
            acc[1][3] = fmaf(a1, b3, acc[1][3]);
            acc[2][0] = fmaf(a2, b0, acc[2][0]);
            acc[2][1] = fmaf(a2, b1, acc[2][1]);
            acc[2][2] = fmaf(a2, b2, acc[2][2]);
            acc[2][3] = fmaf(a2, b3, acc[2][3]);
            acc[3][0] = fmaf(a3, b0, acc[3][0]);
            acc[3][1] = fmaf(a3, b1, acc[3][1]);
            acc[3][2] = fmaf(a3, b2, acc[3][2]);
            acc[3][3] = fmaf(a3, b3, acc[3][3]);
        }
        __syncthreads();
    }

    float bv4[4] = {0.f, 0.f, 0.f, 0.f};
    if (bias) {
        bv4[0] = bias[bn + tn + 0];
        bv4[1] = bias[bn + tn + 1];
        bv4[2] = bias[bn + tn + 2];
        bv4[3] = bias[bn + tn + 3];
    }
#pragma unroll
    for (int i = 0; i < 4; ++i) {
        int r = bm + tm + i;
        if (r < M) {
            float4 o;
            o.x = acc[i][0] + bv4[0];
            o.y = acc[i][1] + bv4[1];
            o.z = acc[i][2] + bv4[2];
            o.w = acc[i][3] + bv4[3];
            if (relu) {
                o.x = fmaxf(o.x, 0.f); o.y = fmaxf(o.y, 0.f);
                o.z = fmaxf(o.z, 0.f); o.w = fmaxf(o.w, 0.f);
            }
            *(float4*)(C + (size_t)r * Nn + bn + tn) = o;
        }
    }
}

// ---- x = relu(agg2 + b2) + hres + bres  (hres already in out, in-place) ----

__global__ __launch_bounds__(256) void final_x_kernel(const float* __restrict__ agg2,
                                                      const float* __restrict__ b2,
                                                      const float* __restrict__ bres,
                                                      float* __restrict__ out, int N) {
    long long tid = (long long)blockIdx.x * blockDim.x + threadIdx.x;
    long long total = (long long)N * 32;
    if (tid >= total) return;
    int f4 = (int)(tid % 32);
    float4 a = *((const float4*)agg2 + tid);
    float4 h = *((float4*)out + tid);
    float4 b = *((const float4*)b2 + f4);
    float4 r = *((const float4*)bres + f4);
    float4 o;
    o.x = fmaxf(a.x + b.x, 0.f) + h.x + r.x;
    o.y = fmaxf(a.y + b.y, 0.f) + h.y + r.y;
    o.z = fmaxf(a.z + b.z, 0.f) + h.z + r.z;
    o.w = fmaxf(a.w + b.w, 0.f) + h.w + r.w;
    *((float4*)out + tid) = o;
}

// ---- MLP head: A[i] = relu(x[i]@Wfc1 + bfc1) @ Wfc2 + bfc2 -----------------

__global__ __launch_bounds__(256) void head_kernel(const float* __restrict__ x,
                                                   const float* __restrict__ Wfc1,
                                                   const float* __restrict__ bfc1,
                                                   const float* __restrict__ Wfc2,
                                                   const float* __restrict__ bfc2,
                                                   float* __restrict__ A, int N) {
    const int NB = 8;
    __shared__ float xs[NB][128];
    __shared__ float red[256];
    const int t = threadIdx.x;
    const int base = blockIdx.x * NB;

    {
        int node = t >> 5;
        int f4   = t & 31;
        float4 v = make_float4(0.f, 0.f, 0.f, 0.f);
        if (base + node < N)
            v = *((const float4*)(x + (size_t)(base + node) * 128) + f4);
        *((float4*)&xs[node][0] + f4) = v;
    }
    __syncthreads();

    float acc[NB] = {};
#pragma unroll 8
    for (int k = 0; k < 128; ++k) {
        float wv = Wfc1[k * 256 + t];
#pragma unroll
        for (int n = 0; n < NB; ++n) acc[n] = fmaf(xs[n][k], wv, acc[n]);
    }
    float bf = bfc1[t];
    float w2 = Wfc2[t];

    for (int n = 0; n < NB; ++n) {
        float p = fmaxf(acc[n] + bf, 0.f) * w2;
        red[t] = p;
        __syncthreads();
        if (t < 128) red[t] += red[t + 128];
        __syncthreads();
        if (t < 64) {
            float v = red[t] + red[t + 64];
            for (int o = 32; o; o >>= 1) v += __shfl_down(v, o);
            if (t == 0 && base + n < N) A[base + n] = v + bfc2[0];
        }
        __syncthreads();
    }
}

// ---------------------------------------------------------------------------

extern "C" void kernel_launch(void* const* d_in, const int* in_sizes, int n_in,
                              void* d_out, int out_size, void* d_ws, size_t ws_size,
                              hipStream_t stream) {
    const float* emb  = (const float*)d_in[0];
    const int*   eidx = (const int*)d_in[1];
    const float* W1   = (const float*)d_in[2];
    const float* b1   = (const float*)d_in[3];
    const float* W2   = (const float*)d_in[4];
    const float* b2   = (const float*)d_in[5];
    const float* Wres = (const float*)d_in[6];
    const float* bres = (const float*)d_in[7];
    const float* Wfc1 = (const float*)d_in[8];
    const float* bfc1 = (const float*)d_in[9];
    const float* Wfc2 = (const float*)d_in[10];
    const float* bfc2 = (const float*)d_in[11];

    const int N = in_sizes[0] / 128;
    const int E = in_sizes[1] / 2;
    const int* srcv = eidx;
    const int* dstv = eidx + E;

    float* out  = (float*)d_out;
    float* xout = out;                       // [N,128]
    float* Aout = out + (size_t)N * 128;     // [N]

    // workspace layout (floats):
    // dinv[N] | aggE[N*128] | x1[N*512] | h2[N*128] | agg2[N*128] |
    // csr_w[E] | ints: cnt[N] excl[N] rowptr[N+1] cursor[N] bsum[256] csr_src[E]
    float* ws    = (float*)d_ws;
    float* dinv  = ws;
    float* aggE  = dinv + N;
    float* x1    = aggE + (size_t)N * 128;
    float* h2    = x1 + (size_t)N * 512;
    float* agg2  = h2 + (size_t)N * 128;
    float* csr_w = agg2 + (size_t)N * 128;
    int*   ibase   = (int*)(csr_w + E);
    int*   cnt     = ibase;
    int*   excl    = cnt + N;
    int*   rowptr  = excl + N;
    int*   cursor  = rowptr + (N + 1);
    int*   bsum    = cursor + N;
    int*   csr_src = bsum + 256;

    const int T  = 256;
    const int nb = cdiv_ll(N, 256);   // 196 blocks for N=50000 (<=256 required)

    // 1) CSR build + dinv
    zero_i32_kernel<<<cdiv_ll(N, T), T, 0, stream>>>(cnt, N);
    hist_kernel<<<cdiv_ll(E, T), T, 0, stream>>>(dstv, cnt, E);
    scanA_kernel<<<nb, T, 0, stream>>>(cnt, excl, bsum, N);
    scanB_kernel<<<1, T, 0, stream>>>(bsum, nb);
    scanC_kernel<<<nb, T, 0, stream>>>(excl, bsum, cnt, rowptr, cursor, dinv, N, E);
    fill_kernel<<<cdiv_ll(E, T), T, 0, stream>>>(srcv, dstv, dinv, cursor, csr_src, csr_w, E);

    // 2) aggE = S @ emb  [N,128]  (layer-1 reorder: S@(X@W) == (S@X)@W)
    agg128_kernel<<<cdiv_ll((long long)N * 64, T), T, 0, stream>>>(
        emb, rowptr, csr_src, csr_w, dinv, aggE, N);

    // 3) x1 = relu(aggE @ W1 + b1)   [N,512]
    sgemm64<<<dim3(512 / 64, cdiv_ll(N, 64)), T, 0, stream>>>(
        aggE, W1, x1, N, 512, 128, b1, 1);

    // 4) h2 = x1 @ W2 [N,128]; hres = x1 @ Wres -> d_out
    sgemm64<<<dim3(128 / 64, cdiv_ll(N, 64)), T, 0, stream>>>(
        x1, W2, h2, N, 128, 512, nullptr, 0);
    sgemm64<<<dim3(128 / 64, cdiv_ll(N, 64)), T, 0, stream>>>(
        x1, Wres, xout, N, 128, 512, nullptr, 0);

    // 5) agg2 = S @ h2  [N,128]
    agg128_kernel<<<cdiv_ll((long long)N * 64, T), T, 0, stream>>>(
        h2, rowptr, csr_src, csr_w, dinv, agg2, N);

    // 6) x = relu(agg2 + b2) + hres + bres
    final_x_kernel<<<cdiv_ll((long long)N * 32, T), T, 0, stream>>>(
        agg2, b2, bres, xout, N);

    // 7) head
    head_kernel<<<cdiv_ll(N, 8), T, 0, stream>>>(xout, Wfc1, bfc1, Wfc2, bfc2, Aout, N);
}

// Round 3
// 340.322 us; speedup vs baseline: 11.2337x; 1.5698x over previous
//
#include <hip/hip_runtime.h>

// ---------------------------------------------------------------------------
// res_rand_GAE round 3: bf16 MFMA GEMMs (fp32 accum), fused W2|Wres GEMM,
// bf16 gather tables for CSR aggregation. Outputs: x [N,128] ++ A [N,1] fp32.
// ---------------------------------------------------------------------------

typedef unsigned short u16;
typedef short bf16x8 __attribute__((ext_vector_type(8)));
typedef unsigned short us8 __attribute__((ext_vector_type(8)));
typedef float f32x4 __attribute__((ext_vector_type(4)));

static inline int cdiv_ll(long long a, long long b) { return (int)((a + b - 1) / b); }

__device__ inline float bf2f(u16 u) {
    union { unsigned int i; float f; } v; v.i = ((unsigned int)u) << 16; return v.f;
}
__device__ inline u16 f2bf(float x) {   // round-to-nearest-even
    union { float f; unsigned int i; } v; v.f = x;
    unsigned int r = v.i + 0x7fffu + ((v.i >> 16) & 1u);
    return (u16)(r >> 16);
}

// ---- CSR build -------------------------------------------------------------

__global__ __launch_bounds__(256) void zero_i32_kernel(int* __restrict__ p, int n) {
    int i = blockIdx.x * 256 + threadIdx.x;
    if (i < n) p[i] = 0;
}

__global__ __launch_bounds__(256) void hist_kernel(const int* __restrict__ dst,
                                                   int* __restrict__ cnt, int E) {
    int e = blockIdx.x * 256 + threadIdx.x;
    if (e < E) atomicAdd(&cnt[dst[e]], 1);
}

__global__ __launch_bounds__(256) void scanA_kernel(const int* __restrict__ cnt,
                                                    int* __restrict__ excl,
                                                    int* __restrict__ bsum, int N) {
    __shared__ int tmp[256];
    int i = blockIdx.x * 256 + threadIdx.x;
    int v = (i < N) ? cnt[i] : 0;
    tmp[threadIdx.x] = v;
    __syncthreads();
    for (int o = 1; o < 256; o <<= 1) {
        int t = (threadIdx.x >= (unsigned)o) ? tmp[threadIdx.x - o] : 0;
        __syncthreads();
        tmp[threadIdx.x] += t;
        __syncthreads();
    }
    if (i < N) excl[i] = tmp[threadIdx.x] - v;
    if (threadIdx.x == 255) bsum[blockIdx.x] = tmp[255];
}

__global__ __launch_bounds__(256) void scanB_kernel(int* __restrict__ bsum, int nb) {
    __shared__ int tmp[256];
    int v = (threadIdx.x < (unsigned)nb) ? bsum[threadIdx.x] : 0;
    tmp[threadIdx.x] = v;
    __syncthreads();
    for (int o = 1; o < 256; o <<= 1) {
        int t = (threadIdx.x >= (unsigned)o) ? tmp[threadIdx.x - o] : 0;
        __syncthreads();
        tmp[threadIdx.x] += t;
        __syncthreads();
    }
    if (threadIdx.x < (unsigned)nb) bsum[threadIdx.x] = tmp[threadIdx.x] - v;
}

__global__ __launch_bounds__(256) void scanC_kernel(const int* __restrict__ excl,
                                                    const int* __restrict__ bsum,
                                                    const int* __restrict__ cnt,
                                                    int* __restrict__ rowptr,
                                                    int* __restrict__ cursor,
                                                    float* __restrict__ dinv,
                                                    int N, int E) {
    int i = blockIdx.x * 256 + threadIdx.x;
    if (i < N) {
        int r = excl[i] + bsum[blockIdx.x];
        rowptr[i] = r;
        cursor[i] = r;
        dinv[i] = rsqrtf((float)cnt[i] + 2.0f);
    }
    if (i == 0) rowptr[N] = E;
}

__global__ __launch_bounds__(256) void fill_kernel(const int* __restrict__ src,
                                                   const int* __restrict__ dst,
                                                   const float* __restrict__ dinv,
                                                   int* __restrict__ cursor,
                                                   int* __restrict__ csr_src,
                                                   float* __restrict__ csr_w, int E) {
    int e = blockIdx.x * 256 + threadIdx.x;
    if (e >= E) return;
    int s = src[e], d = dst[e];
    int idx = atomicAdd(&cursor[d], 1);
    csr_src[idx] = s;
    csr_w[idx] = dinv[s] * dinv[d];
}

// ---- conversions -----------------------------------------------------------

// fp32 [n4*4] -> bf16, vectorized float4 -> 4x u16
__global__ __launch_bounds__(256) void f2b_kernel(const float* __restrict__ x,
                                                  u16* __restrict__ y, long long n4) {
    long long tid = (long long)blockIdx.x * 256 + threadIdx.x;
    if (tid >= n4) return;
    float4 v = ((const float4*)x)[tid];
    uint2 o;
    o.x = (unsigned)f2bf(v.x) | ((unsigned)f2bf(v.y) << 16);
    o.y = (unsigned)f2bf(v.z) | ((unsigned)f2bf(v.w) << 16);
    ((uint2*)y)[tid] = o;
}

// W [K][Nn] fp32 -> Wt [Nn][K] bf16
__global__ __launch_bounds__(256) void wtrans_kernel(const float* __restrict__ W,
                                                     u16* __restrict__ Wt, int K, int Nn) {
    int tid = blockIdx.x * 256 + threadIdx.x;
    if (tid >= K * Nn) return;
    int n = tid / K, k = tid % K;
    Wt[tid] = f2bf(W[(size_t)k * Nn + n]);
}

// Wcat_t [256][512] bf16 from W2 [512][128], Wres [512][128]
__global__ __launch_bounds__(256) void wcat_kernel(const float* __restrict__ W2,
                                                   const float* __restrict__ Wres,
                                                   u16* __restrict__ Wt, int K) {
    int tid = blockIdx.x * 256 + threadIdx.x;
    if (tid >= 256 * K) return;
    int n = tid / K, k = tid % K;
    float v = (n < 128) ? W2[(size_t)k * 128 + n] : Wres[(size_t)k * 128 + (n - 128)];
    Wt[tid] = f2bf(v);
}

// ---- wave-per-node aggregation over bf16 table [N][128] --------------------
// out[i] = 2*dinv[i]^2 * h[i] + sum_e w_e * h[src_e];   OUT_BF16: bf16 or f32

template <int OUT_BF16>
__global__ __launch_bounds__(256) void aggb_kernel(const u16* __restrict__ hb,
                                                   const int* __restrict__ rowptr,
                                                   const int* __restrict__ csr_src,
                                                   const float* __restrict__ csr_w,
                                                   const float* __restrict__ dinv,
                                                   void* __restrict__ out, int N) {
    int wid  = (blockIdx.x * blockDim.x + threadIdx.x) >> 6;
    int lane = threadIdx.x & 63;
    if (wid >= N) return;
    const unsigned int* hp = (const unsigned int*)hb;  // 2 bf16 per uint
    float dv = dinv[wid];
    unsigned int hv = hp[(size_t)wid * 64 + lane];
    float c0 = 2.0f * dv * dv;
    float ax = bf2f((u16)hv) * c0;
    float ay = bf2f((u16)(hv >> 16)) * c0;
    int e = rowptr[wid], e1 = rowptr[wid + 1];
    for (; e + 1 < e1; e += 2) {
        int s0 = csr_src[e], s1 = csr_src[e + 1];
        float w0 = csr_w[e], w1 = csr_w[e + 1];
        unsigned int v0 = hp[(size_t)s0 * 64 + lane];
        unsigned int v1 = hp[(size_t)s1 * 64 + lane];
        ax = fmaf(bf2f((u16)v0), w0, ax);
        ay = fmaf(bf2f((u16)(v0 >> 16)), w0, ay);
        ax = fmaf(bf2f((u16)v1), w1, ax);
        ay = fmaf(bf2f((u16)(v1 >> 16)), w1, ay);
    }
    if (e < e1) {
        int s0 = csr_src[e]; float w0 = csr_w[e];
        unsigned int v0 = hp[(size_t)s0 * 64 + lane];
        ax = fmaf(bf2f((u16)v0), w0, ax);
        ay = fmaf(bf2f((u16)(v0 >> 16)), w0, ay);
    }
    if (OUT_BF16) {
        unsigned int o = (unsigned)f2bf(ax) | ((unsigned)f2bf(ay) << 16);
        ((unsigned int*)out)[(size_t)wid * 64 + lane] = o;
    } else {
        ((float2*)out)[(size_t)wid * 64 + lane] = make_float2(ax, ay);
    }
}

// ---- bf16 MFMA GEMM: C = A[M][K] @ Bt[Nn][K]^T -----------------------------
// BM=128 BN=64 BK=64, 256 threads = 4 waves (2x2), 16x16x32 MFMA, fp32 acc.
// MODE 1: x1 = relu(C + bias) -> bf16 Cb [M][Nn]
// MODE 2: col<128 -> bf16 Cb [M][128] (h2); col>=128 -> f32 Cf [M][128] (hres)

template <int MODE>
__global__ __launch_bounds__(256) void mgemm(const u16* __restrict__ A,
                                             const u16* __restrict__ Bt,
                                             int M, int Nn, int K,
                                             const float* __restrict__ bias,
                                             u16* __restrict__ Cb,
                                             float* __restrict__ Cf) {
    __shared__ u16 As[128][72];   // +8 pad: 144B rows, 16B-aligned, 2-way banks
    __shared__ u16 Bs[64][72];
    const int t = threadIdx.x;
    const int bm = blockIdx.y * 128;
    const int bn = blockIdx.x * 64;
    const int w = t >> 6, lane = t & 63;
    const int wm = w >> 1, wn = w & 1;
    const int l15 = lane & 15, lg = lane >> 4;

    f32x4 acc[4][2];
#pragma unroll
    for (int i = 0; i < 4; ++i)
#pragma unroll
        for (int j = 0; j < 2; ++j) acc[i][j] = (f32x4)(0.0f);

    for (int kk = 0; kk < K; kk += 64) {
#pragma unroll
        for (int i = 0; i < 4; ++i) {           // A tile: 128x64
            int c = t + 256 * i;
            int row = c >> 3, cs = (c & 7) * 8;
            us8 v = (us8)(u16)0;
            if (bm + row < M)
                v = *(const us8*)(A + (size_t)(bm + row) * K + kk + cs);
            *(us8*)&As[row][cs] = v;
        }
#pragma unroll
        for (int i = 0; i < 2; ++i) {           // B tile: 64x64 (rows of Bt)
            int c = t + 256 * i;
            int row = c >> 3, cs = (c & 7) * 8;
            us8 v = *(const us8*)(Bt + (size_t)(bn + row) * K + kk + cs);
            *(us8*)&Bs[row][cs] = v;
        }
        __syncthreads();
#pragma unroll
        for (int ks = 0; ks < 2; ++ks) {
            const int ko = 32 * ks + lg * 8;
            bf16x8 bfr[2], afr[4];
#pragma unroll
            for (int fn = 0; fn < 2; ++fn)
                bfr[fn] = *(const bf16x8*)&Bs[32 * wn + 16 * fn + l15][ko];
#pragma unroll
            for (int fm = 0; fm < 4; ++fm)
                afr[fm] = *(const bf16x8*)&As[64 * wm + 16 * fm + l15][ko];
#pragma unroll
            for (int fm = 0; fm < 4; ++fm)
#pragma unroll
                for (int fn = 0; fn < 2; ++fn)
                    acc[fm][fn] = __builtin_amdgcn_mfma_f32_16x16x32_bf16(
                        afr[fm], bfr[fn], acc[fm][fn], 0, 0, 0);
        }
        __syncthreads();
    }

#pragma unroll
    for (int fm = 0; fm < 4; ++fm) {
#pragma unroll
        for (int fn = 0; fn < 2; ++fn) {
            const int col = bn + 32 * wn + 16 * fn + l15;
#pragma unroll
            for (int r = 0; r < 4; ++r) {
                int row = bm + 64 * wm + 16 * fm + lg * 4 + r;
                if (row < M) {
                    float v = acc[fm][fn][r];
                    if (MODE == 1) {
                        v = fmaxf(v + bias[col], 0.0f);
                        Cb[(size_t)row * Nn + col] = f2bf(v);
                    } else {
                        if (col < 128) Cb[(size_t)row * 128 + col] = f2bf(v);
                        else           Cf[(size_t)row * 128 + (col - 128)] = v;
                    }
                }
            }
        }
    }
}

// ---- x = relu(agg2 + b2) + hres + bres  (hres already in out, in-place) ----

__global__ __launch_bounds__(256) void final_x_kernel(const float* __restrict__ agg2,
                                                      const float* __restrict__ b2,
                                                      const float* __restrict__ bres,
                                                      float* __restrict__ out, int N) {
    long long tid = (long long)blockIdx.x * blockDim.x + threadIdx.x;
    long long total = (long long)N * 32;
    if (tid >= total) return;
    int f4 = (int)(tid % 32);
    float4 a = *((const float4*)agg2 + tid);
    float4 h = *((float4*)out + tid);
    float4 b = *((const float4*)b2 + f4);
    float4 r = *((const float4*)bres + f4);
    float4 o;
    o.x = fmaxf(a.x + b.x, 0.f) + h.x + r.x;
    o.y = fmaxf(a.y + b.y, 0.f) + h.y + r.y;
    o.z = fmaxf(a.z + b.z, 0.f) + h.z + r.z;
    o.w = fmaxf(a.w + b.w, 0.f) + h.w + r.w;
    *((float4*)out + tid) = o;
}

// ---- MLP head (fp32 exact): A[i] = relu(x[i]@Wfc1+bfc1)@Wfc2 + bfc2 --------

__global__ __launch_bounds__(256) void head_kernel(const float* __restrict__ x,
                                                   const float* __restrict__ Wfc1,
                                                   const float* __restrict__ bfc1,
                                                   const float* __restrict__ Wfc2,
                                                   const float* __restrict__ bfc2,
                                                   float* __restrict__ A, int N) {
    const int NB = 8;
    __shared__ float xs[NB][128];
    __shared__ float red[256];
    const int t = threadIdx.x;
    const int base = blockIdx.x * NB;

    {
        int node = t >> 5;
        int f4   = t & 31;
        float4 v = make_float4(0.f, 0.f, 0.f, 0.f);
        if (base + node < N)
            v = *((const float4*)(x + (size_t)(base + node) * 128) + f4);
        *((float4*)&xs[node][0] + f4) = v;
    }
    __syncthreads();

    float acc[NB] = {};
#pragma unroll 8
    for (int k = 0; k < 128; ++k) {
        float wv = Wfc1[k * 256 + t];
#pragma unroll
        for (int n = 0; n < NB; ++n) acc[n] = fmaf(xs[n][k], wv, acc[n]);
    }
    float bf = bfc1[t];
    float w2 = Wfc2[t];

    for (int n = 0; n < NB; ++n) {
        float p = fmaxf(acc[n] + bf, 0.f) * w2;
        red[t] = p;
        __syncthreads();
        if (t < 128) red[t] += red[t + 128];
        __syncthreads();
        if (t < 64) {
            float v = red[t] + red[t + 64];
            for (int o = 32; o; o >>= 1) v += __shfl_down(v, o);
            if (t == 0 && base + n < N) A[base + n] = v + bfc2[0];
        }
        __syncthreads();
    }
}

// ---------------------------------------------------------------------------

extern "C" void kernel_launch(void* const* d_in, const int* in_sizes, int n_in,
                              void* d_out, int out_size, void* d_ws, size_t ws_size,
                              hipStream_t stream) {
    const float* emb  = (const float*)d_in[0];
    const int*   eidx = (const int*)d_in[1];
    const float* W1   = (const float*)d_in[2];
    const float* b1   = (const float*)d_in[3];
    const float* W2   = (const float*)d_in[4];
    const float* b2   = (const float*)d_in[5];
    const float* Wres = (const float*)d_in[6];
    const float* bres = (const float*)d_in[7];
    const float* Wfc1 = (const float*)d_in[8];
    const float* bfc1 = (const float*)d_in[9];
    const float* Wfc2 = (const float*)d_in[10];
    const float* bfc2 = (const float*)d_in[11];

    const int N = in_sizes[0] / 128;
    const int E = in_sizes[1] / 2;
    const int* srcv = eidx;
    const int* dstv = eidx + E;

    float* out  = (float*)d_out;
    float* xout = out;                       // [N,128]
    float* Aout = out + (size_t)N * 128;     // [N]

    // ---- workspace layout (bytes, all regions 16B-aligned) ----
    char* p = (char*)d_ws;
    float* dinv  = (float*)p;            p += (size_t)N * 4;            // N%4==0
    float* agg2  = (float*)p;            p += (size_t)N * 128 * 4;
    float* csr_w = (float*)p;            p += (size_t)E * 4;
    u16*  embb   = (u16*)p;              p += (size_t)N * 128 * 2;
    u16*  aggEb  = (u16*)p;              p += (size_t)N * 128 * 2;
    u16*  x1b    = (u16*)p;              p += (size_t)N * 512 * 2;
    u16*  h2b    = (u16*)p;              p += (size_t)N * 128 * 2;
    u16*  W1t    = (u16*)p;              p += (size_t)512 * 128 * 2;
    u16*  Wct    = (u16*)p;              p += (size_t)256 * 512 * 2;
    int*  cnt     = (int*)p;             p += (size_t)N * 4;
    int*  excl    = (int*)p;             p += (size_t)N * 4;
    int*  rowptr  = (int*)p;             p += (size_t)(N + 1) * 4;
    int*  cursor  = (int*)p;             p += (size_t)N * 4;
    int*  bsum    = (int*)p;             p += 256 * 4;
    int*  csr_src = (int*)p;             p += (size_t)E * 4;

    const int T  = 256;
    const int nb = cdiv_ll(N, 256);      // <= 256 required by scanB

    // 1) CSR build + dinv
    zero_i32_kernel<<<cdiv_ll(N, T), T, 0, stream>>>(cnt, N);
    hist_kernel<<<cdiv_ll(E, T), T, 0, stream>>>(dstv, cnt, E);
    scanA_kernel<<<nb, T, 0, stream>>>(cnt, excl, bsum, N);
    scanB_kernel<<<1, T, 0, stream>>>(bsum, nb);
    scanC_kernel<<<nb, T, 0, stream>>>(excl, bsum, cnt, rowptr, cursor, dinv, N, E);
    fill_kernel<<<cdiv_ll(E, T), T, 0, stream>>>(srcv, dstv, dinv, cursor, csr_src, csr_w, E);

    // 2) conversions: emb -> bf16 table; weights -> transposed bf16
    f2b_kernel<<<cdiv_ll((long long)N * 32, T), T, 0, stream>>>(emb, embb, (long long)N * 32);
    wtrans_kernel<<<cdiv_ll(128 * 512, T), T, 0, stream>>>(W1, W1t, 128, 512);
    wcat_kernel<<<cdiv_ll(256 * 512, T), T, 0, stream>>>(W2, Wres, Wct, 512);

    // 3) aggE = S @ emb  (bf16 out)
    aggb_kernel<1><<<cdiv_ll((long long)N * 64, T), T, 0, stream>>>(
        embb, rowptr, csr_src, csr_w, dinv, aggEb, N);

    // 4) x1 = relu(aggE @ W1 + b1) -> bf16 [N,512]
    mgemm<1><<<dim3(512 / 64, cdiv_ll(N, 128)), T, 0, stream>>>(
        aggEb, W1t, N, 512, 128, b1, x1b, nullptr);

    // 5) fused: h2 = x1@W2 (bf16), hres = x1@Wres (fp32 -> xout)
    mgemm<2><<<dim3(256 / 64, cdiv_ll(N, 128)), T, 0, stream>>>(
        x1b, Wct, N, 256, 512, nullptr, h2b, xout);

    // 6) agg2 = S @ h2  (fp32 out)
    aggb_kernel<0><<<cdiv_ll((long long)N * 64, T), T, 0, stream>>>(
        h2b, rowptr, csr_src, csr_w, dinv, agg2, N);

    // 7) x = relu(agg2 + b2) + hres + bres
    final_x_kernel<<<cdiv_ll((long long)N * 32, T), T, 0, stream>>>(
        agg2, b2, bres, xout, N);

    // 8) head (fp32 exact)
    head_kernel<<<cdiv_ll(N, 8), T, 0, stream>>>(xout, Wfc1, bfc1, Wfc2, bfc2, Aout, N);
}

// Round 4
// 277.436 us; speedup vs baseline: 13.7800x; 1.2267x over previous
//
#include <hip/hip_runtime.h>

// ---------------------------------------------------------------------------
// res_rand_GAE round 4: all three GEMMs on bf16 MFMA (fp32 accum); head's
// *Wfc2 dot fused into the MFMA epilogue (atomicAdd); agg2+final_x fused.
// Outputs: x [N,128] ++ A [N,1] fp32 in d_out.
// ---------------------------------------------------------------------------

typedef unsigned short u16;
typedef short bf16x8 __attribute__((ext_vector_type(8)));
typedef unsigned short us8 __attribute__((ext_vector_type(8)));
typedef float f32x4 __attribute__((ext_vector_type(4)));

static inline int cdiv_ll(long long a, long long b) { return (int)((a + b - 1) / b); }

__device__ inline float bf2f(u16 u) {
    union { unsigned int i; float f; } v; v.i = ((unsigned int)u) << 16; return v.f;
}
__device__ inline u16 f2bf(float x) {   // round-to-nearest-even
    union { float f; unsigned int i; } v; v.f = x;
    unsigned int r = v.i + 0x7fffu + ((v.i >> 16) & 1u);
    return (u16)(r >> 16);
}

// ---- CSR build -------------------------------------------------------------

__global__ __launch_bounds__(256) void zero_i32_kernel(int* __restrict__ p, int n) {
    int i = blockIdx.x * 256 + threadIdx.x;
    if (i < n) p[i] = 0;
}

__global__ __launch_bounds__(256) void hist_kernel(const int* __restrict__ dst,
                                                   int* __restrict__ cnt, int E) {
    int e = blockIdx.x * 256 + threadIdx.x;
    if (e < E) atomicAdd(&cnt[dst[e]], 1);
}

__global__ __launch_bounds__(256) void scanA_kernel(const int* __restrict__ cnt,
                                                    int* __restrict__ excl,
                                                    int* __restrict__ bsum, int N) {
    __shared__ int tmp[256];
    int i = blockIdx.x * 256 + threadIdx.x;
    int v = (i < N) ? cnt[i] : 0;
    tmp[threadIdx.x] = v;
    __syncthreads();
    for (int o = 1; o < 256; o <<= 1) {
        int t = (threadIdx.x >= (unsigned)o) ? tmp[threadIdx.x - o] : 0;
        __syncthreads();
        tmp[threadIdx.x] += t;
        __syncthreads();
    }
    if (i < N) excl[i] = tmp[threadIdx.x] - v;
    if (threadIdx.x == 255) bsum[blockIdx.x] = tmp[255];
}

__global__ __launch_bounds__(256) void scanB_kernel(int* __restrict__ bsum, int nb) {
    __shared__ int tmp[256];
    int v = (threadIdx.x < (unsigned)nb) ? bsum[threadIdx.x] : 0;
    tmp[threadIdx.x] = v;
    __syncthreads();
    for (int o = 1; o < 256; o <<= 1) {
        int t = (threadIdx.x >= (unsigned)o) ? tmp[threadIdx.x - o] : 0;
        __syncthreads();
        tmp[threadIdx.x] += t;
        __syncthreads();
    }
    if (threadIdx.x < (unsigned)nb) bsum[threadIdx.x] = tmp[threadIdx.x] - v;
}

__global__ __launch_bounds__(256) void scanC_kernel(const int* __restrict__ excl,
                                                    const int* __restrict__ bsum,
                                                    const int* __restrict__ cnt,
                                                    int* __restrict__ rowptr,
                                                    int* __restrict__ cursor,
                                                    float* __restrict__ dinv,
                                                    int N, int E) {
    int i = blockIdx.x * 256 + threadIdx.x;
    if (i < N) {
        int r = excl[i] + bsum[blockIdx.x];
        rowptr[i] = r;
        cursor[i] = r;
        dinv[i] = rsqrtf((float)cnt[i] + 2.0f);
    }
    if (i == 0) rowptr[N] = E;
}

__global__ __launch_bounds__(256) void fill_kernel(const int* __restrict__ src,
                                                   const int* __restrict__ dst,
                                                   const float* __restrict__ dinv,
                                                   int* __restrict__ cursor,
                                                   int* __restrict__ csr_src,
                                                   float* __restrict__ csr_w, int E) {
    int e = blockIdx.x * 256 + threadIdx.x;
    if (e >= E) return;
    int s = src[e], d = dst[e];
    int idx = atomicAdd(&cursor[d], 1);
    csr_src[idx] = s;
    csr_w[idx] = dinv[s] * dinv[d];
}

// ---- conversions -----------------------------------------------------------

__global__ __launch_bounds__(256) void f2b_kernel(const float* __restrict__ x,
                                                  u16* __restrict__ y, long long n4) {
    long long tid = (long long)blockIdx.x * 256 + threadIdx.x;
    if (tid >= n4) return;
    float4 v = ((const float4*)x)[tid];
    uint2 o;
    o.x = (unsigned)f2bf(v.x) | ((unsigned)f2bf(v.y) << 16);
    o.y = (unsigned)f2bf(v.z) | ((unsigned)f2bf(v.w) << 16);
    ((uint2*)y)[tid] = o;
}

// W [K][Nn] fp32 -> Wt [Nn][K] bf16
__global__ __launch_bounds__(256) void wtrans_kernel(const float* __restrict__ W,
                                                     u16* __restrict__ Wt, int K, int Nn) {
    int tid = blockIdx.x * 256 + threadIdx.x;
    if (tid >= K * Nn) return;
    int n = tid / K, k = tid % K;
    Wt[tid] = f2bf(W[(size_t)k * Nn + n]);
}

// Wcat_t [256][512] bf16 from W2 [512][128], Wres [512][128]
__global__ __launch_bounds__(256) void wcat_kernel(const float* __restrict__ W2,
                                                   const float* __restrict__ Wres,
                                                   u16* __restrict__ Wt, int K) {
    int tid = blockIdx.x * 256 + threadIdx.x;
    if (tid >= 256 * K) return;
    int n = tid / K, k = tid % K;
    float v = (n < 128) ? W2[(size_t)k * 128 + n] : Wres[(size_t)k * 128 + (n - 128)];
    Wt[tid] = f2bf(v);
}

__global__ __launch_bounds__(256) void initA_kernel(float* __restrict__ A,
                                                    const float* __restrict__ bfc2, int N) {
    int i = blockIdx.x * 256 + threadIdx.x;
    if (i < N) A[i] = bfc2[0];
}

// ---- wave-per-node CSR aggregation over bf16 table [N][128] ----------------
// acc = 2*dinv[i]^2 * h[i] + sum_e w_e * h[src_e]

__device__ inline void agg_row(const unsigned int* __restrict__ hp,
                               const int* __restrict__ rowptr,
                               const int* __restrict__ csr_src,
                               const float* __restrict__ csr_w,
                               const float* __restrict__ dinv,
                               int wid, int lane, float& ax, float& ay) {
    float dv = dinv[wid];
    unsigned int hv = hp[(size_t)wid * 64 + lane];
    float c0 = 2.0f * dv * dv;
    ax = bf2f((u16)hv) * c0;
    ay = bf2f((u16)(hv >> 16)) * c0;
    int e = rowptr[wid], e1 = rowptr[wid + 1];
    for (; e + 3 < e1; e += 4) {
        int s0 = csr_src[e], s1 = csr_src[e + 1], s2 = csr_src[e + 2], s3 = csr_src[e + 3];
        float w0 = csr_w[e], w1 = csr_w[e + 1], w2 = csr_w[e + 2], w3 = csr_w[e + 3];
        unsigned int v0 = hp[(size_t)s0 * 64 + lane];
        unsigned int v1 = hp[(size_t)s1 * 64 + lane];
        unsigned int v2 = hp[(size_t)s2 * 64 + lane];
        unsigned int v3 = hp[(size_t)s3 * 64 + lane];
        ax = fmaf(bf2f((u16)v0), w0, ax); ay = fmaf(bf2f((u16)(v0 >> 16)), w0, ay);
        ax = fmaf(bf2f((u16)v1), w1, ax); ay = fmaf(bf2f((u16)(v1 >> 16)), w1, ay);
        ax = fmaf(bf2f((u16)v2), w2, ax); ay = fmaf(bf2f((u16)(v2 >> 16)), w2, ay);
        ax = fmaf(bf2f((u16)v3), w3, ax); ay = fmaf(bf2f((u16)(v3 >> 16)), w3, ay);
    }
    for (; e < e1; ++e) {
        int s0 = csr_src[e]; float w0 = csr_w[e];
        unsigned int v0 = hp[(size_t)s0 * 64 + lane];
        ax = fmaf(bf2f((u16)v0), w0, ax); ay = fmaf(bf2f((u16)(v0 >> 16)), w0, ay);
    }
}

// plain agg -> bf16 table
__global__ __launch_bounds__(256) void aggb_kernel(const u16* __restrict__ hb,
                                                   const int* __restrict__ rowptr,
                                                   const int* __restrict__ csr_src,
                                                   const float* __restrict__ csr_w,
                                                   const float* __restrict__ dinv,
                                                   u16* __restrict__ out, int N) {
    int wid  = (blockIdx.x * blockDim.x + threadIdx.x) >> 6;
    int lane = threadIdx.x & 63;
    if (wid >= N) return;
    float ax, ay;
    agg_row((const unsigned int*)hb, rowptr, csr_src, csr_w, dinv, wid, lane, ax, ay);
    ((unsigned int*)out)[(size_t)wid * 64 + lane] =
        (unsigned)f2bf(ax) | ((unsigned)f2bf(ay) << 16);
}

// fused: x = relu(agg(h2) + b2) + hres + bres -> xout fp32 AND xb bf16
__global__ __launch_bounds__(256) void aggfin_kernel(const u16* __restrict__ hb,
                                                     const int* __restrict__ rowptr,
                                                     const int* __restrict__ csr_src,
                                                     const float* __restrict__ csr_w,
                                                     const float* __restrict__ dinv,
                                                     const float* __restrict__ b2,
                                                     const float* __restrict__ bres,
                                                     float* __restrict__ xout,
                                                     u16* __restrict__ xb, int N) {
    int wid  = (blockIdx.x * blockDim.x + threadIdx.x) >> 6;
    int lane = threadIdx.x & 63;
    if (wid >= N) return;
    float ax, ay;
    agg_row((const unsigned int*)hb, rowptr, csr_src, csr_w, dinv, wid, lane, ax, ay);
    float2 bb = ((const float2*)b2)[lane];
    float2 rr = ((const float2*)bres)[lane];
    float2 hres = ((float2*)xout)[(size_t)wid * 64 + lane];
    float ox = fmaxf(ax + bb.x, 0.f) + hres.x + rr.x;
    float oy = fmaxf(ay + bb.y, 0.f) + hres.y + rr.y;
    ((float2*)xout)[(size_t)wid * 64 + lane] = make_float2(ox, oy);
    ((unsigned int*)xb)[(size_t)wid * 64 + lane] =
        (unsigned)f2bf(ox) | ((unsigned)f2bf(oy) << 16);
}

// ---- bf16 MFMA GEMM: C = A[M][K] @ Bt[Nn][K]^T -----------------------------
// BM=128 BN=64 BK=64, 256 threads = 4 waves (2x2), 16x16x32 MFMA, fp32 acc.
// MODE 1: Cb = bf16(relu(C + bias))            [M][Nn]
// MODE 2: col<128 -> Cb bf16 [M][128]; col>=128 -> Cf f32 [M][128]
// MODE 3: Cf[row] += sum_col relu(C + bias[col]) * w2[col]   (atomic)

template <int MODE>
__global__ __launch_bounds__(256) void mgemm(const u16* __restrict__ A,
                                             const u16* __restrict__ Bt,
                                             int M, int Nn, int K,
                                             const float* __restrict__ bias,
                                             u16* __restrict__ Cb,
                                             float* __restrict__ Cf,
                                             const float* __restrict__ w2) {
    __shared__ u16 As[128][72];   // +8 pad: 144B rows, 16B-aligned
    __shared__ u16 Bs[64][72];
    const int t = threadIdx.x;
    const int bm = blockIdx.y * 128;
    const int bn = blockIdx.x * 64;
    const int w = t >> 6, lane = t & 63;
    const int wm = w >> 1, wn = w & 1;
    const int l15 = lane & 15, lg = lane >> 4;

    f32x4 acc[4][2];
#pragma unroll
    for (int i = 0; i < 4; ++i)
#pragma unroll
        for (int j = 0; j < 2; ++j) acc[i][j] = (f32x4)(0.0f);

    for (int kk = 0; kk < K; kk += 64) {
#pragma unroll
        for (int i = 0; i < 4; ++i) {           // A tile: 128x64
            int c = t + 256 * i;
            int row = c >> 3, cs = (c & 7) * 8;
            us8 v = (us8)(u16)0;
            if (bm + row < M)
                v = *(const us8*)(A + (size_t)(bm + row) * K + kk + cs);
            *(us8*)&As[row][cs] = v;
        }
#pragma unroll
        for (int i = 0; i < 2; ++i) {           // B tile: 64x64 (rows of Bt)
            int c = t + 256 * i;
            int row = c >> 3, cs = (c & 7) * 8;
            us8 v = *(const us8*)(Bt + (size_t)(bn + row) * K + kk + cs);
            *(us8*)&Bs[row][cs] = v;
        }
        __syncthreads();
#pragma unroll
        for (int ks = 0; ks < 2; ++ks) {
            const int ko = 32 * ks + lg * 8;
            bf16x8 bfr[2], afr[4];
#pragma unroll
            for (int fn = 0; fn < 2; ++fn)
                bfr[fn] = *(const bf16x8*)&Bs[32 * wn + 16 * fn + l15][ko];
#pragma unroll
            for (int fm = 0; fm < 4; ++fm)
                afr[fm] = *(const bf16x8*)&As[64 * wm + 16 * fm + l15][ko];
#pragma unroll
            for (int fm = 0; fm < 4; ++fm)
#pragma unroll
                for (int fn = 0; fn < 2; ++fn)
                    acc[fm][fn] = __builtin_amdgcn_mfma_f32_16x16x32_bf16(
                        afr[fm], bfr[fn], acc[fm][fn], 0, 0, 0);
        }
        __syncthreads();
    }

    if (MODE == 3) {
        const int c0 = bn + 32 * wn + l15;
        const float b0 = bias[c0], b1 = bias[c0 + 16];
        const float w20 = w2[c0], w21 = w2[c0 + 16];
#pragma unroll
        for (int fm = 0; fm < 4; ++fm) {
#pragma unroll
            for (int r = 0; r < 4; ++r) {
                int row = bm + 64 * wm + 16 * fm + lg * 4 + r;
                float p = fmaxf(acc[fm][0][r] + b0, 0.f) * w20
                        + fmaxf(acc[fm][1][r] + b1, 0.f) * w21;
                p += __shfl_xor(p, 1);
                p += __shfl_xor(p, 2);
                p += __shfl_xor(p, 4);
                p += __shfl_xor(p, 8);
                if (l15 == 0 && row < M) atomicAdd(&Cf[row], p);
            }
        }
        return;
    }

#pragma unroll
    for (int fm = 0; fm < 4; ++fm) {
#pragma unroll
        for (int fn = 0; fn < 2; ++fn) {
            const int col = bn + 32 * wn + 16 * fn + l15;
#pragma unroll
            for (int r = 0; r < 4; ++r) {
                int row = bm + 64 * wm + 16 * fm + lg * 4 + r;
                if (row < M) {
                    float v = acc[fm][fn][r];
                    if (MODE == 1) {
                        v = fmaxf(v + bias[col], 0.0f);
                        Cb[(size_t)row * Nn + col] = f2bf(v);
                    } else {
                        if (col < 128) Cb[(size_t)row * 128 + col] = f2bf(v);
                        else           Cf[(size_t)row * 128 + (col - 128)] = v;
                    }
                }
            }
        }
    }
}

// ---------------------------------------------------------------------------

extern "C" void kernel_launch(void* const* d_in, const int* in_sizes, int n_in,
                              void* d_out, int out_size, void* d_ws, size_t ws_size,
                              hipStream_t stream) {
    const float* emb  = (const float*)d_in[0];
    const int*   eidx = (const int*)d_in[1];
    const float* W1   = (const float*)d_in[2];
    const float* b1   = (const float*)d_in[3];
    const float* W2   = (const float*)d_in[4];
    const float* b2   = (const float*)d_in[5];
    const float* Wres = (const float*)d_in[6];
    const float* bres = (const float*)d_in[7];
    const float* Wfc1 = (const float*)d_in[8];
    const float* bfc1 = (const float*)d_in[9];
    const float* Wfc2 = (const float*)d_in[10];
    const float* bfc2 = (const float*)d_in[11];

    const int N = in_sizes[0] / 128;
    const int E = in_sizes[1] / 2;
    const int* srcv = eidx;
    const int* dstv = eidx + E;

    float* out  = (float*)d_out;
    float* xout = out;                       // [N,128]
    float* Aout = out + (size_t)N * 128;     // [N]

    // ---- workspace layout ----
    char* p = (char*)d_ws;
    float* dinv  = (float*)p;            p += (size_t)N * 4;
    float* csr_w = (float*)p;            p += (size_t)E * 4;
    u16*  embb   = (u16*)p;              p += (size_t)N * 128 * 2;
    u16*  aggEb  = (u16*)p;              p += (size_t)N * 128 * 2;
    u16*  x1b    = (u16*)p;              p += (size_t)N * 512 * 2;
    u16*  h2b    = (u16*)p;              p += (size_t)N * 128 * 2;
    u16*  xb     = (u16*)p;              p += (size_t)N * 128 * 2;
    u16*  W1t    = (u16*)p;              p += (size_t)512 * 128 * 2;
    u16*  Wct    = (u16*)p;              p += (size_t)256 * 512 * 2;
    u16*  Wfc1t  = (u16*)p;              p += (size_t)256 * 128 * 2;
    int*  cnt     = (int*)p;             p += (size_t)N * 4;
    int*  excl    = (int*)p;             p += (size_t)N * 4;
    int*  rowptr  = (int*)p;             p += (size_t)(N + 1) * 4;
    int*  cursor  = (int*)p;             p += (size_t)N * 4;
    int*  bsum    = (int*)p;             p += 256 * 4;
    int*  csr_src = (int*)p;             p += (size_t)E * 4;

    const int T  = 256;
    const int nb = cdiv_ll(N, 256);      // <= 256 required by scanB

    // 1) CSR build + dinv
    zero_i32_kernel<<<cdiv_ll(N, T), T, 0, stream>>>(cnt, N);
    hist_kernel<<<cdiv_ll(E, T), T, 0, stream>>>(dstv, cnt, E);
    scanA_kernel<<<nb, T, 0, stream>>>(cnt, excl, bsum, N);
    scanB_kernel<<<1, T, 0, stream>>>(bsum, nb);
    scanC_kernel<<<nb, T, 0, stream>>>(excl, bsum, cnt, rowptr, cursor, dinv, N, E);
    fill_kernel<<<cdiv_ll(E, T), T, 0, stream>>>(srcv, dstv, dinv, cursor, csr_src, csr_w, E);

    // 2) conversions
    f2b_kernel<<<cdiv_ll((long long)N * 32, T), T, 0, stream>>>(emb, embb, (long long)N * 32);
    wtrans_kernel<<<cdiv_ll(128 * 512, T), T, 0, stream>>>(W1, W1t, 128, 512);
    wcat_kernel<<<cdiv_ll(256 * 512, T), T, 0, stream>>>(W2, Wres, Wct, 512);
    wtrans_kernel<<<cdiv_ll(128 * 256, T), T, 0, stream>>>(Wfc1, Wfc1t, 128, 256);
    initA_kernel<<<cdiv_ll(N, T), T, 0, stream>>>(Aout, bfc2, N);

    // 3) aggE = S @ emb  (bf16)
    aggb_kernel<<<cdiv_ll((long long)N * 64, T), T, 0, stream>>>(
        embb, rowptr, csr_src, csr_w, dinv, aggEb, N);

    // 4) x1 = relu(aggE @ W1 + b1) -> bf16 [N,512]
    mgemm<1><<<dim3(512 / 64, cdiv_ll(N, 128)), T, 0, stream>>>(
        aggEb, W1t, N, 512, 128, b1, x1b, nullptr, nullptr);

    // 5) fused: h2 = x1@W2 (bf16), hres = x1@Wres (fp32 -> xout)
    mgemm<2><<<dim3(256 / 64, cdiv_ll(N, 128)), T, 0, stream>>>(
        x1b, Wct, N, 256, 512, nullptr, h2b, xout, nullptr);

    // 6) fused: x = relu(S@h2 + b2) + hres + bres -> xout (fp32) + xb (bf16)
    aggfin_kernel<<<cdiv_ll((long long)N * 64, T), T, 0, stream>>>(
        h2b, rowptr, csr_src, csr_w, dinv, b2, bres, xout, xb, N);

    // 7) head: A += sum relu(xb@Wfc1t + bfc1) * Wfc2  (A pre-init to bfc2)
    mgemm<3><<<dim3(256 / 64, cdiv_ll(N, 128)), T, 0, stream>>>(
        xb, Wfc1t, N, 256, 128, bfc1, nullptr, Aout, Wfc2);
}

// Round 5
// 215.649 us; speedup vs baseline: 17.7282x; 1.2865x over previous
//
#include <hip/hip_runtime.h>

// ---------------------------------------------------------------------------
// res_rand_GAE round 5: MFMA GEMMs retiled to BM=128 x BN=256 (512 thr,
// 8 waves 2x4) to kill the 4x/8x A-panel re-fetch seen in rocprof
// (FETCH_SIZE 181 MB vs 51 MB unique). Everything else as round 4.
// ---------------------------------------------------------------------------

typedef unsigned short u16;
typedef short bf16x8 __attribute__((ext_vector_type(8)));
typedef unsigned short us8 __attribute__((ext_vector_type(8)));
typedef float f32x4 __attribute__((ext_vector_type(4)));

static inline int cdiv_ll(long long a, long long b) { return (int)((a + b - 1) / b); }

__device__ inline float bf2f(u16 u) {
    union { unsigned int i; float f; } v; v.i = ((unsigned int)u) << 16; return v.f;
}
__device__ inline u16 f2bf(float x) {   // round-to-nearest-even
    union { float f; unsigned int i; } v; v.f = x;
    unsigned int r = v.i + 0x7fffu + ((v.i >> 16) & 1u);
    return (u16)(r >> 16);
}

// ---- CSR build -------------------------------------------------------------

__global__ __launch_bounds__(256) void zero_i32_kernel(int* __restrict__ p, int n) {
    int i = blockIdx.x * 256 + threadIdx.x;
    if (i < n) p[i] = 0;
}

__global__ __launch_bounds__(256) void hist_kernel(const int* __restrict__ dst,
                                                   int* __restrict__ cnt, int E) {
    int e = blockIdx.x * 256 + threadIdx.x;
    if (e < E) atomicAdd(&cnt[dst[e]], 1);
}

__global__ __launch_bounds__(256) void scanA_kernel(const int* __restrict__ cnt,
                                                    int* __restrict__ excl,
                                                    int* __restrict__ bsum, int N) {
    __shared__ int tmp[256];
    int i = blockIdx.x * 256 + threadIdx.x;
    int v = (i < N) ? cnt[i] : 0;
    tmp[threadIdx.x] = v;
    __syncthreads();
    for (int o = 1; o < 256; o <<= 1) {
        int t = (threadIdx.x >= (unsigned)o) ? tmp[threadIdx.x - o] : 0;
        __syncthreads();
        tmp[threadIdx.x] += t;
        __syncthreads();
    }
    if (i < N) excl[i] = tmp[threadIdx.x] - v;
    if (threadIdx.x == 255) bsum[blockIdx.x] = tmp[255];
}

__global__ __launch_bounds__(256) void scanB_kernel(int* __restrict__ bsum, int nb) {
    __shared__ int tmp[256];
    int v = (threadIdx.x < (unsigned)nb) ? bsum[threadIdx.x] : 0;
    tmp[threadIdx.x] = v;
    __syncthreads();
    for (int o = 1; o < 256; o <<= 1) {
        int t = (threadIdx.x >= (unsigned)o) ? tmp[threadIdx.x - o] : 0;
        __syncthreads();
        tmp[threadIdx.x] += t;
        __syncthreads();
    }
    if (threadIdx.x < (unsigned)nb) bsum[threadIdx.x] = tmp[threadIdx.x] - v;
}

__global__ __launch_bounds__(256) void scanC_kernel(const int* __restrict__ excl,
                                                    const int* __restrict__ bsum,
                                                    const int* __restrict__ cnt,
                                                    int* __restrict__ rowptr,
                                                    int* __restrict__ cursor,
                                                    float* __restrict__ dinv,
                                                    int N, int E) {
    int i = blockIdx.x * 256 + threadIdx.x;
    if (i < N) {
        int r = excl[i] + bsum[blockIdx.x];
        rowptr[i] = r;
        cursor[i] = r;
        dinv[i] = rsqrtf((float)cnt[i] + 2.0f);
    }
    if (i == 0) rowptr[N] = E;
}

__global__ __launch_bounds__(256) void fill_kernel(const int* __restrict__ src,
                                                   const int* __restrict__ dst,
                                                   const float* __restrict__ dinv,
                                                   int* __restrict__ cursor,
                                                   int* __restrict__ csr_src,
                                                   float* __restrict__ csr_w, int E) {
    int e = blockIdx.x * 256 + threadIdx.x;
    if (e >= E) return;
    int s = src[e], d = dst[e];
    int idx = atomicAdd(&cursor[d], 1);
    csr_src[idx] = s;
    csr_w[idx] = dinv[s] * dinv[d];
}

// ---- conversions -----------------------------------------------------------

__global__ __launch_bounds__(256) void f2b_kernel(const float* __restrict__ x,
                                                  u16* __restrict__ y, long long n4) {
    long long tid = (long long)blockIdx.x * 256 + threadIdx.x;
    if (tid >= n4) return;
    float4 v = ((const float4*)x)[tid];
    uint2 o;
    o.x = (unsigned)f2bf(v.x) | ((unsigned)f2bf(v.y) << 16);
    o.y = (unsigned)f2bf(v.z) | ((unsigned)f2bf(v.w) << 16);
    ((uint2*)y)[tid] = o;
}

// W [K][Nn] fp32 -> Wt [Nn][K] bf16
__global__ __launch_bounds__(256) void wtrans_kernel(const float* __restrict__ W,
                                                     u16* __restrict__ Wt, int K, int Nn) {
    int tid = blockIdx.x * 256 + threadIdx.x;
    if (tid >= K * Nn) return;
    int n = tid / K, k = tid % K;
    Wt[tid] = f2bf(W[(size_t)k * Nn + n]);
}

// Wcat_t [256][512] bf16 from W2 [512][128], Wres [512][128]
__global__ __launch_bounds__(256) void wcat_kernel(const float* __restrict__ W2,
                                                   const float* __restrict__ Wres,
                                                   u16* __restrict__ Wt, int K) {
    int tid = blockIdx.x * 256 + threadIdx.x;
    if (tid >= 256 * K) return;
    int n = tid / K, k = tid % K;
    float v = (n < 128) ? W2[(size_t)k * 128 + n] : Wres[(size_t)k * 128 + (n - 128)];
    Wt[tid] = f2bf(v);
}

__global__ __launch_bounds__(256) void initA_kernel(float* __restrict__ A,
                                                    const float* __restrict__ bfc2, int N) {
    int i = blockIdx.x * 256 + threadIdx.x;
    if (i < N) A[i] = bfc2[0];
}

// ---- wave-per-node CSR aggregation over bf16 table [N][128] ----------------

__device__ inline void agg_row(const unsigned int* __restrict__ hp,
                               const int* __restrict__ rowptr,
                               const int* __restrict__ csr_src,
                               const float* __restrict__ csr_w,
                               const float* __restrict__ dinv,
                               int wid, int lane, float& ax, float& ay) {
    float dv = dinv[wid];
    unsigned int hv = hp[(size_t)wid * 64 + lane];
    float c0 = 2.0f * dv * dv;
    ax = bf2f((u16)hv) * c0;
    ay = bf2f((u16)(hv >> 16)) * c0;
    int e = rowptr[wid], e1 = rowptr[wid + 1];
    for (; e + 3 < e1; e += 4) {
        int s0 = csr_src[e], s1 = csr_src[e + 1], s2 = csr_src[e + 2], s3 = csr_src[e + 3];
        float w0 = csr_w[e], w1 = csr_w[e + 1], w2 = csr_w[e + 2], w3 = csr_w[e + 3];
        unsigned int v0 = hp[(size_t)s0 * 64 + lane];
        unsigned int v1 = hp[(size_t)s1 * 64 + lane];
        unsigned int v2 = hp[(size_t)s2 * 64 + lane];
        unsigned int v3 = hp[(size_t)s3 * 64 + lane];
        ax = fmaf(bf2f((u16)v0), w0, ax); ay = fmaf(bf2f((u16)(v0 >> 16)), w0, ay);
        ax = fmaf(bf2f((u16)v1), w1, ax); ay = fmaf(bf2f((u16)(v1 >> 16)), w1, ay);
        ax = fmaf(bf2f((u16)v2), w2, ax); ay = fmaf(bf2f((u16)(v2 >> 16)), w2, ay);
        ax = fmaf(bf2f((u16)v3), w3, ax); ay = fmaf(bf2f((u16)(v3 >> 16)), w3, ay);
    }
    for (; e < e1; ++e) {
        int s0 = csr_src[e]; float w0 = csr_w[e];
        unsigned int v0 = hp[(size_t)s0 * 64 + lane];
        ax = fmaf(bf2f((u16)v0), w0, ax); ay = fmaf(bf2f((u16)(v0 >> 16)), w0, ay);
    }
}

__global__ __launch_bounds__(256) void aggb_kernel(const u16* __restrict__ hb,
                                                   const int* __restrict__ rowptr,
                                                   const int* __restrict__ csr_src,
                                                   const float* __restrict__ csr_w,
                                                   const float* __restrict__ dinv,
                                                   u16* __restrict__ out, int N) {
    int wid  = (blockIdx.x * blockDim.x + threadIdx.x) >> 6;
    int lane = threadIdx.x & 63;
    if (wid >= N) return;
    float ax, ay;
    agg_row((const unsigned int*)hb, rowptr, csr_src, csr_w, dinv, wid, lane, ax, ay);
    ((unsigned int*)out)[(size_t)wid * 64 + lane] =
        (unsigned)f2bf(ax) | ((unsigned)f2bf(ay) << 16);
}

// fused: x = relu(agg(h2) + b2) + hres + bres -> xout fp32 AND xb bf16
__global__ __launch_bounds__(256) void aggfin_kernel(const u16* __restrict__ hb,
                                                     const int* __restrict__ rowptr,
                                                     const int* __restrict__ csr_src,
                                                     const float* __restrict__ csr_w,
                                                     const float* __restrict__ dinv,
                                                     const float* __restrict__ b2,
                                                     const float* __restrict__ bres,
                                                     float* __restrict__ xout,
                                                     u16* __restrict__ xb, int N) {
    int wid  = (blockIdx.x * blockDim.x + threadIdx.x) >> 6;
    int lane = threadIdx.x & 63;
    if (wid >= N) return;
    float ax, ay;
    agg_row((const unsigned int*)hb, rowptr, csr_src, csr_w, dinv, wid, lane, ax, ay);
    float2 bb = ((const float2*)b2)[lane];
    float2 rr = ((const float2*)bres)[lane];
    float2 hres = ((float2*)xout)[(size_t)wid * 64 + lane];
    float ox = fmaxf(ax + bb.x, 0.f) + hres.x + rr.x;
    float oy = fmaxf(ay + bb.y, 0.f) + hres.y + rr.y;
    ((float2*)xout)[(size_t)wid * 64 + lane] = make_float2(ox, oy);
    ((unsigned int*)xb)[(size_t)wid * 64 + lane] =
        (unsigned)f2bf(ox) | ((unsigned)f2bf(oy) << 16);
}

// ---- bf16 MFMA GEMM: C = A[M][K] @ Bt[Nn][K]^T -----------------------------
// BM=128 BN=256 BK=64, 512 threads = 8 waves (2 row x 4 col), 16x16x32 MFMA.
// MODE 1: Cb = bf16(relu(C + bias))            [M][Nn]
// MODE 2: col<128 -> Cb bf16 [M][128]; col>=128 -> Cf f32 [M][128]
// MODE 3: Cf[row] += sum_col relu(C + bias[col]) * w2[col]   (atomic)

template <int MODE>
__global__ __launch_bounds__(512) void mgemm(const u16* __restrict__ A,
                                             const u16* __restrict__ Bt,
                                             int M, int Nn, int K,
                                             const float* __restrict__ bias,
                                             u16* __restrict__ Cb,
                                             float* __restrict__ Cf,
                                             const float* __restrict__ w2) {
    __shared__ u16 As[128][72];   // 18.4 KB (+8 pad, 16B-aligned rows)
    __shared__ u16 Bs[256][72];   // 36.9 KB
    const int t = threadIdx.x;
    const int bm = blockIdx.y * 128;
    const int bn = blockIdx.x * 256;
    const int w = t >> 6, lane = t & 63;
    const int wm = w >> 2, wn = w & 3;        // 2 x 4 wave grid
    const int l15 = lane & 15, lg = lane >> 4;

    f32x4 acc[4][4];
#pragma unroll
    for (int i = 0; i < 4; ++i)
#pragma unroll
        for (int j = 0; j < 4; ++j) acc[i][j] = (f32x4)(0.0f);

    for (int kk = 0; kk < K; kk += 64) {
#pragma unroll
        for (int i = 0; i < 2; ++i) {           // A tile: 128x64 (1024 vec8)
            int c = t + 512 * i;
            int row = c >> 3, cs = (c & 7) * 8;
            us8 v = (us8)(u16)0;
            if (bm + row < M)
                v = *(const us8*)(A + (size_t)(bm + row) * K + kk + cs);
            *(us8*)&As[row][cs] = v;
        }
#pragma unroll
        for (int i = 0; i < 4; ++i) {           // B tile: 256x64 (2048 vec8)
            int c = t + 512 * i;
            int row = c >> 3, cs = (c & 7) * 8;
            us8 v = *(const us8*)(Bt + (size_t)(bn + row) * K + kk + cs);
            *(us8*)&Bs[row][cs] = v;
        }
        __syncthreads();
#pragma unroll
        for (int ks = 0; ks < 2; ++ks) {
            const int ko = 32 * ks + lg * 8;
            bf16x8 bfr[4], afr[4];
#pragma unroll
            for (int fn = 0; fn < 4; ++fn)
                bfr[fn] = *(const bf16x8*)&Bs[64 * wn + 16 * fn + l15][ko];
#pragma unroll
            for (int fm = 0; fm < 4; ++fm)
                afr[fm] = *(const bf16x8*)&As[64 * wm + 16 * fm + l15][ko];
#pragma unroll
            for (int fm = 0; fm < 4; ++fm)
#pragma unroll
                for (int fn = 0; fn < 4; ++fn)
                    acc[fm][fn] = __builtin_amdgcn_mfma_f32_16x16x32_bf16(
                        afr[fm], bfr[fn], acc[fm][fn], 0, 0, 0);
        }
        __syncthreads();
    }

    if (MODE == 3) {
        float bl[4], wl[4];
#pragma unroll
        for (int fn = 0; fn < 4; ++fn) {
            int col = bn + 64 * wn + 16 * fn + l15;
            bl[fn] = bias[col];
            wl[fn] = w2[col];
        }
#pragma unroll
        for (int fm = 0; fm < 4; ++fm) {
#pragma unroll
            for (int r = 0; r < 4; ++r) {
                int row = bm + 64 * wm + 16 * fm + lg * 4 + r;
                float p = 0.f;
#pragma unroll
                for (int fn = 0; fn < 4; ++fn)
                    p += fmaxf(acc[fm][fn][r] + bl[fn], 0.f) * wl[fn];
                p += __shfl_xor(p, 1);
                p += __shfl_xor(p, 2);
                p += __shfl_xor(p, 4);
                p += __shfl_xor(p, 8);
                if (l15 == 0 && row < M) atomicAdd(&Cf[row], p);
            }
        }
        return;
    }

#pragma unroll
    for (int fm = 0; fm < 4; ++fm) {
#pragma unroll
        for (int fn = 0; fn < 4; ++fn) {
            const int col = bn + 64 * wn + 16 * fn + l15;
#pragma unroll
            for (int r = 0; r < 4; ++r) {
                int row = bm + 64 * wm + 16 * fm + lg * 4 + r;
                if (row < M) {
                    float v = acc[fm][fn][r];
                    if (MODE == 1) {
                        v = fmaxf(v + bias[col], 0.0f);
                        Cb[(size_t)row * Nn + col] = f2bf(v);
                    } else {
                        if (col < 128) Cb[(size_t)row * 128 + col] = f2bf(v);
                        else           Cf[(size_t)row * 128 + (col - 128)] = v;
                    }
                }
            }
        }
    }
}

// ---------------------------------------------------------------------------

extern "C" void kernel_launch(void* const* d_in, const int* in_sizes, int n_in,
                              void* d_out, int out_size, void* d_ws, size_t ws_size,
                              hipStream_t stream) {
    const float* emb  = (const float*)d_in[0];
    const int*   eidx = (const int*)d_in[1];
    const float* W1   = (const float*)d_in[2];
    const float* b1   = (const float*)d_in[3];
    const float* W2   = (const float*)d_in[4];
    const float* b2   = (const float*)d_in[5];
    const float* Wres = (const float*)d_in[6];
    const float* bres = (const float*)d_in[7];
    const float* Wfc1 = (const float*)d_in[8];
    const float* bfc1 = (const float*)d_in[9];
    const float* Wfc2 = (const float*)d_in[10];
    const float* bfc2 = (const float*)d_in[11];

    const int N = in_sizes[0] / 128;
    const int E = in_sizes[1] / 2;
    const int* srcv = eidx;
    const int* dstv = eidx + E;

    float* out  = (float*)d_out;
    float* xout = out;                       // [N,128]
    float* Aout = out + (size_t)N * 128;     // [N]

    // ---- workspace layout ----
    char* p = (char*)d_ws;
    float* dinv  = (float*)p;            p += (size_t)N * 4;
    float* csr_w = (float*)p;            p += (size_t)E * 4;
    u16*  embb   = (u16*)p;              p += (size_t)N * 128 * 2;
    u16*  aggEb  = (u16*)p;              p += (size_t)N * 128 * 2;
    u16*  x1b    = (u16*)p;              p += (size_t)N * 512 * 2;
    u16*  h2b    = (u16*)p;              p += (size_t)N * 128 * 2;
    u16*  xb     = (u16*)p;              p += (size_t)N * 128 * 2;
    u16*  W1t    = (u16*)p;              p += (size_t)512 * 128 * 2;
    u16*  Wct    = (u16*)p;              p += (size_t)256 * 512 * 2;
    u16*  Wfc1t  = (u16*)p;              p += (size_t)256 * 128 * 2;
    int*  cnt     = (int*)p;             p += (size_t)N * 4;
    int*  excl    = (int*)p;             p += (size_t)N * 4;
    int*  rowptr  = (int*)p;             p += (size_t)(N + 1) * 4;
    int*  cursor  = (int*)p;             p += (size_t)N * 4;
    int*  bsum    = (int*)p;             p += 256 * 4;
    int*  csr_src = (int*)p;             p += (size_t)E * 4;

    const int T  = 256;
    const int nb = cdiv_ll(N, 256);      // <= 256 required by scanB

    // 1) CSR build + dinv
    zero_i32_kernel<<<cdiv_ll(N, T), T, 0, stream>>>(cnt, N);
    hist_kernel<<<cdiv_ll(E, T), T, 0, stream>>>(dstv, cnt, E);
    scanA_kernel<<<nb, T, 0, stream>>>(cnt, excl, bsum, N);
    scanB_kernel<<<1, T, 0, stream>>>(bsum, nb);
    scanC_kernel<<<nb, T, 0, stream>>>(excl, bsum, cnt, rowptr, cursor, dinv, N, E);
    fill_kernel<<<cdiv_ll(E, T), T, 0, stream>>>(srcv, dstv, dinv, cursor, csr_src, csr_w, E);

    // 2) conversions
    f2b_kernel<<<cdiv_ll((long long)N * 32, T), T, 0, stream>>>(emb, embb, (long long)N * 32);
    wtrans_kernel<<<cdiv_ll(128 * 512, T), T, 0, stream>>>(W1, W1t, 128, 512);
    wcat_kernel<<<cdiv_ll(256 * 512, T), T, 0, stream>>>(W2, Wres, Wct, 512);
    wtrans_kernel<<<cdiv_ll(128 * 256, T), T, 0, stream>>>(Wfc1, Wfc1t, 128, 256);
    initA_kernel<<<cdiv_ll(N, T), T, 0, stream>>>(Aout, bfc2, N);

    // 3) aggE = S @ emb  (bf16)
    aggb_kernel<<<cdiv_ll((long long)N * 64, T), T, 0, stream>>>(
        embb, rowptr, csr_src, csr_w, dinv, aggEb, N);

    // 4) x1 = relu(aggE @ W1 + b1) -> bf16 [N,512]
    mgemm<1><<<dim3(512 / 256, cdiv_ll(N, 128)), 512, 0, stream>>>(
        aggEb, W1t, N, 512, 128, b1, x1b, nullptr, nullptr);

    // 5) fused: h2 = x1@W2 (bf16), hres = x1@Wres (fp32 -> xout)
    mgemm<2><<<dim3(1, cdiv_ll(N, 128)), 512, 0, stream>>>(
        x1b, Wct, N, 256, 512, nullptr, h2b, xout, nullptr);

    // 6) fused: x = relu(S@h2 + b2) + hres + bres -> xout (fp32) + xb (bf16)
    aggfin_kernel<<<cdiv_ll((long long)N * 64, T), T, 0, stream>>>(
        h2b, rowptr, csr_src, csr_w, dinv, b2, bres, xout, xb, N);

    // 7) head: A += sum relu(xb@Wfc1t + bfc1) * Wfc2  (A pre-init to bfc2)
    mgemm<3><<<dim3(1, cdiv_ll(N, 128)), 512, 0, stream>>>(
        xb, Wfc1t, N, 256, 128, bfc1, nullptr, Aout, Wfc2);
}